// Round 4
// baseline (1490.124 us; speedup 1.0000x reference)
//
#include <hip/hip_runtime.h>

#define B_   32
#define T_   300
#define C1_  2312
#define O1_  512
#define O2_  512
#define O3_  10
#define M_   (B_*T_)   // 9600

// ---------------- weight prep (all f64) ----------------

__global__ void calc_f(const float* __restrict__ v, const float* __restrict__ g,
                       double* __restrict__ f, int O, int C) {
    int o = blockIdx.x;
    const float* row = v + (size_t)o * C;
    double s = 0.0;
    for (int c = threadIdx.x; c < C; c += blockDim.x) {
        double x = (double)row[c];
        s += x * x;
    }
    for (int off = 32; off; off >>= 1) s += __shfl_down(s, off);
    __shared__ double wsum[4];
    int lane = threadIdx.x & 63, wv = threadIdx.x >> 6;
    if (lane == 0) wsum[wv] = s;
    __syncthreads();
    if (threadIdx.x == 0) {
        double tot = 0.0;
        for (int i = 0; i < (int)(blockDim.x >> 6); ++i) tot += wsum[i];
        f[o] = (double)g[o] / sqrt(tot);
    }
}

// wt[c*ldo + o] = v[o*C + c] * f[o]   (double)
__global__ void transpose_scale(const float* __restrict__ v, const double* __restrict__ f,
                                double* __restrict__ wt, int O, int C, int ldo) {
    __shared__ double tile[32][33];
    int c0 = blockIdx.x * 32, o0 = blockIdx.y * 32;
    int tx = threadIdx.x, ty = threadIdx.y;
    for (int k = 0; k < 4; ++k) {
        int o = o0 + ty + k * 8, c = c0 + tx;
        double val = 0.0;
        if (o < O && c < C) val = (double)v[(size_t)o * C + c] * f[o];
        tile[ty + k * 8][tx] = val;
    }
    __syncthreads();
    for (int k = 0; k < 4; ++k) {
        int c = c0 + ty + k * 8, o = o0 + tx;
        if (c < C && o < O) wt[(size_t)c * ldo + o] = tile[tx][ty + k * 8];
    }
}

// ---------------- GEMM layer 1 (f64 acc, conflict-free strided tile) ----------------
// X: spike [B, C1, T] f32 ; Wt: [C1, O1] f64 ; Z: [B, T, O1] f64
// tile 128o x 64t, 128 threads, micro 8x8: thread o's = to+16i (to=tid&15),
// thread t's = tt*8+j (tt=tid>>4). wf read = 8x ds_read_b64 lane-contiguous (no conflict).
#define G1_KC 16
__global__ __launch_bounds__(128) void gemm1(const float* __restrict__ X,
                                             const double* __restrict__ Wt,
                                             double* __restrict__ Z) {
    __shared__ double Ws[G1_KC][128];
    __shared__ double Xs[G1_KC][64];
    int b  = blockIdx.z;
    int o0 = blockIdx.y * 128;
    int t0 = blockIdx.x * 64;
    int tid = threadIdx.x;
    int to = tid & 15, tt = tid >> 4;
    double acc[8][8];
#pragma unroll
    for (int i = 0; i < 8; ++i)
#pragma unroll
        for (int j = 0; j < 8; ++j) acc[i][j] = 0.0;
    const float* Xb = X + (size_t)b * C1_ * T_;
    for (int c0 = 0; c0 < C1_; c0 += G1_KC) {
        {   // Xs: 16x64 f32->f64. Thread covers 8 consecutive j in one row i.
            int e = tid * 8;
            int i = e >> 6, j = e & 63;
            int c = c0 + i, t = t0 + j;
            float4 v0 = make_float4(0.f, 0.f, 0.f, 0.f);
            float4 v1 = make_float4(0.f, 0.f, 0.f, 0.f);
            if (c < C1_) {   // T_%4==0, j%8==0 -> float4 never straddles the t<T_ edge
                if (t < T_)     v0 = *(const float4*)(Xb + (size_t)c * T_ + t);
                if (t + 4 < T_) v1 = *(const float4*)(Xb + (size_t)c * T_ + t + 4);
            }
            Xs[i][j + 0] = (double)v0.x; Xs[i][j + 1] = (double)v0.y;
            Xs[i][j + 2] = (double)v0.z; Xs[i][j + 3] = (double)v0.w;
            Xs[i][j + 4] = (double)v1.x; Xs[i][j + 5] = (double)v1.y;
            Xs[i][j + 6] = (double)v1.z; Xs[i][j + 7] = (double)v1.w;
        }
        {   // Ws: 16x128 f64. Thread owns row i = tid>>3, o-range (tid&7)*16..+15.
            int i = tid >> 3, ob = (tid & 7) * 16;
            int c = c0 + i;
            if (c < C1_) {
                const double* src = Wt + (size_t)c * O1_ + o0 + ob;
#pragma unroll
                for (int q = 0; q < 8; ++q)
                    *(double2*)(&Ws[i][ob + q * 2]) = *(const double2*)(src + q * 2);
            } else {
#pragma unroll
                for (int q = 0; q < 16; ++q) Ws[i][ob + q] = 0.0;
            }
        }
        __syncthreads();
#pragma unroll
        for (int k = 0; k < G1_KC; ++k) {
            double wf[8], xf[8];
#pragma unroll
            for (int i = 0; i < 8; ++i) wf[i] = Ws[k][to + 16 * i];
#pragma unroll
            for (int j = 0; j < 4; ++j)
                *(double2*)(&xf[j * 2]) = *(const double2*)(&Xs[k][tt * 8 + j * 2]);
#pragma unroll
            for (int i = 0; i < 8; ++i)
#pragma unroll
                for (int j = 0; j < 8; ++j) acc[i][j] = fma(wf[i], xf[j], acc[i][j]);
        }
        __syncthreads();
    }
#pragma unroll
    for (int j = 0; j < 8; ++j) {
        int t = t0 + tt * 8 + j;
        if (t < T_) {
            double* dst = Z + ((size_t)b * T_ + t) * O1_ + o0;
#pragma unroll
            for (int i = 0; i < 8; ++i) dst[to + 16 * i] = acc[i][j];
        }
    }
}

// ---------------- GEMM layer 2 (f64 acc, same structure) ----------------
// A: s1 [M, 512] f32 (exact 0/1) ; Wt: [512, 512] f64 ; Z: [M, 512] f64
// tile 64m x 128o, 128 threads, micro 8x8 strided.
__global__ __launch_bounds__(128) void gemm2(const float* __restrict__ A,
                                             const double* __restrict__ Wt,
                                             double* __restrict__ Z) {
    __shared__ double Ws[G1_KC][128];
    __shared__ double As[G1_KC][64];
    int m0 = blockIdx.x * 64;
    int o0 = blockIdx.y * 128;
    int tid = threadIdx.x;
    int to = tid & 15, tm = tid >> 4;
    double acc[8][8];
#pragma unroll
    for (int i = 0; i < 8; ++i)
#pragma unroll
        for (int j = 0; j < 8; ++j) acc[i][j] = 0.0;
    for (int c0 = 0; c0 < 512; c0 += G1_KC) {
        {   // As: 16c x 64m transposed. Thread m = tid&63, c-half = tid>>6.
            int m = tid & 63, ch = (tid >> 6) * 8;
            const float* src = A + (size_t)(m0 + m) * 512 + c0 + ch;
            float4 v0 = *(const float4*)(src);
            float4 v1 = *(const float4*)(src + 4);
            As[ch + 0][m] = (double)v0.x; As[ch + 1][m] = (double)v0.y;
            As[ch + 2][m] = (double)v0.z; As[ch + 3][m] = (double)v0.w;
            As[ch + 4][m] = (double)v1.x; As[ch + 5][m] = (double)v1.y;
            As[ch + 6][m] = (double)v1.z; As[ch + 7][m] = (double)v1.w;
        }
        {   // Ws: 16x128 f64, same as gemm1 (K=512, always in range)
            int i = tid >> 3, ob = (tid & 7) * 16;
            const double* src = Wt + (size_t)(c0 + i) * 512 + o0 + ob;
#pragma unroll
            for (int q = 0; q < 8; ++q)
                *(double2*)(&Ws[i][ob + q * 2]) = *(const double2*)(src + q * 2);
        }
        __syncthreads();
#pragma unroll
        for (int k = 0; k < G1_KC; ++k) {
            double wf[8], xf[8];
#pragma unroll
            for (int i = 0; i < 8; ++i) wf[i] = Ws[k][to + 16 * i];
#pragma unroll
            for (int j = 0; j < 4; ++j)
                *(double2*)(&xf[j * 2]) = *(const double2*)(&As[k][tm * 8 + j * 2]);
#pragma unroll
            for (int i = 0; i < 8; ++i)
#pragma unroll
                for (int j = 0; j < 8; ++j) acc[i][j] = fma(wf[i], xf[j], acc[i][j]);
        }
        __syncthreads();
    }
#pragma unroll
    for (int j = 0; j < 8; ++j) {
        double* dst = Z + (size_t)(m0 + tm * 8 + j) * 512 + o0;
#pragma unroll
        for (int i = 0; i < 8; ++i) dst[to + 16 * i] = acc[i][j];
    }
}

// ---------------- GEMM layer 3 (f64 acc) ----------------
__global__ __launch_bounds__(256) void gemm3(const float* __restrict__ A,
                                             const double* __restrict__ Wt,
                                             double* __restrict__ Z) {
    __shared__ double w[512 * 16];
    for (int e = threadIdx.x; e < 4096; e += 256)
        ((double2*)w)[e] = ((const double2*)Wt)[e];
    __syncthreads();
    int m = blockIdx.x * 256 + threadIdx.x;
    if (m >= M_) return;
    double acc[O3_];
#pragma unroll
    for (int o = 0; o < O3_; ++o) acc[o] = 0.0;
    const float4* Ar = (const float4*)(A + (size_t)m * 512);
    for (int cq = 0; cq < 128; ++cq) {
        float4 a = Ar[cq];
        float av[4] = {a.x, a.y, a.z, a.w};
#pragma unroll
        for (int u = 0; u < 4; ++u)
#pragma unroll
            for (int o = 0; o < O3_; ++o) acc[o] += (double)av[u] * w[(cq * 4 + u) * 16 + o];
    }
    double* dst = Z + (size_t)m * 16;
#pragma unroll
    for (int o = 0; o < O3_; ++o) dst[o] = acc[o];
}

// ---------------- LIF scan + delay, layers 1/2 (O=512, f64 state) ----------------
// 256 blocks x 64 threads: full-CU coverage; 4-batched loads for MLP.
__global__ void scan12(const double* __restrict__ Zin,  // [B, T, 512] f64
                       const int* __restrict__ delay,   // [512]
                       float* __restrict__ Sout,        // [B, T, 512] f32 spikes
                       float* __restrict__ sumOut) {
    int blk = blockIdx.x;
    int o = (blk & 7) * 64 + threadIdx.x;
    int b = blk >> 3;
    const double* z = Zin + (size_t)b * T_ * O1_ + o;
    float* s = Sout + (size_t)b * T_ * O1_ + o;
    int d = delay[o];
    for (int t = 0; t < d; ++t) s[(size_t)t * O1_] = 0.f;
    double cur = 0.0, vol = 0.0;
    float cnt = 0.f;
    for (int t4 = 0; t4 < T_; t4 += 4) {
        double zb[4];
#pragma unroll
        for (int u = 0; u < 4; ++u) zb[u] = z[(size_t)(t4 + u) * O1_];
#pragma unroll
        for (int u = 0; u < 4; ++u) {
            int t = t4 + u;
            cur = cur * 0.75 + zb[u];
            vol = vol * 0.97 + cur;
            float sp = (vol >= 1.25) ? 1.f : 0.f;
            if (sp > 0.f) vol = 0.0;
            int tw = t + d;
            if (tw < T_) { s[(size_t)tw * O1_] = sp; cnt += sp; }
        }
    }
    for (int off = 32; off; off >>= 1) cnt += __shfl_down(cnt, off);
    if (threadIdx.x == 0) atomicAdd(sumOut, cnt);
}

// ---------------- LIF scan + delay, layer 3 (O=10, f64 state) ----------------
__global__ void scan3(const double* __restrict__ Z3,  // [M, 16] f64
                      const int* __restrict__ d3,     // [10]
                      float* __restrict__ out,        // d_out: [B, 10, 300] f32
                      float* __restrict__ sumOut) {
    __shared__ double zt[T_ * 16];
    int b = blockIdx.x;
    const double2* src = (const double2*)(Z3 + (size_t)b * T_ * 16);
    for (int e = threadIdx.x; e < T_ * 8; e += 64)
        ((double2*)zt)[e] = src[e];
    __syncthreads();
    int o = threadIdx.x;
    if (o < O3_) {
        int d = d3[o];
        float* dst = out + (size_t)b * O3_ * T_ + (size_t)o * T_;
        for (int t = 0; t < d; ++t) dst[t] = 0.f;
        double cur = 0.0, vol = 0.0;
        float cnt = 0.f;
        for (int t = 0; t < T_; ++t) {
            cur = cur * 0.75 + zt[t * 16 + o];
            vol = vol * 0.97 + cur;
            float sp = (vol >= 1.25) ? 1.f : 0.f;
            if (sp > 0.f) vol = 0.0;
            int tw = t + d;
            if (tw < T_) { dst[tw] = sp; cnt += sp; }
        }
        atomicAdd(sumOut, cnt);
    }
}

__global__ void finalize(const float* __restrict__ sums, float* __restrict__ out) {
    if (threadIdx.x == 0) {
        out[0] = (float)((double)sums[0] / (double)(B_ * O1_ * T_));
        out[1] = (float)((double)sums[1] / (double)(B_ * O2_ * T_));
        out[2] = (float)((double)sums[2] / (double)(B_ * O3_ * T_));
    }
}

extern "C" void kernel_launch(void* const* d_in, const int* in_sizes, int n_in,
                              void* d_out, int out_size, void* d_ws, size_t ws_size,
                              hipStream_t stream) {
    const float* spike = (const float*)d_in[0];
    const float* v1 = (const float*)d_in[1];
    const float* g1 = (const float*)d_in[2];
    const float* v2 = (const float*)d_in[3];
    const float* g2 = (const float*)d_in[4];
    const float* v3 = (const float*)d_in[5];
    const float* g3 = (const float*)d_in[6];
    const int* d1 = (const int*)d_in[7];
    const int* d2 = (const int*)d_in[8];
    const int* d3 = (const int*)d_in[9];
    float* out = (float*)d_out;

    // Workspace (same layout as R3 pass): ~72 MB total.
    double* dw = (double*)d_ws;
    size_t off = 0;
    double* f1  = dw + off; off += 512;
    double* f2  = dw + off; off += 512;
    double* f3  = dw + off; off += 16;
    double* Wt1 = dw + off; off += (size_t)C1_ * O1_;
    double* Wt2 = dw + off; off += 512 * 512;
    double* Wt3 = dw + off; off += 512 * 16;
    double* zA  = dw + off; off += (size_t)M_ * 512;
    double* z3b = dw + off; off += (size_t)M_ * 16;
    float* fw = (float*)(dw + off);
    float* sB   = fw;                        // f32 spikes, M*512
    float* sums = fw + (size_t)M_ * 512;     // 4 floats
    (void)ws_size; (void)out_size; (void)in_sizes; (void)n_in;

    hipMemsetAsync(sums, 0, 4 * sizeof(float), stream);

    calc_f<<<512, 256, 0, stream>>>(v1, g1, f1, O1_, C1_);
    calc_f<<<512, 256, 0, stream>>>(v2, g2, f2, O2_, O1_);
    calc_f<<<O3_, 256, 0, stream>>>(v3, g3, f3, O3_, O2_);

    transpose_scale<<<dim3((C1_ + 31) / 32, 16), dim3(32, 8), 0, stream>>>(v1, f1, Wt1, O1_, C1_, O1_);
    transpose_scale<<<dim3(16, 16), dim3(32, 8), 0, stream>>>(v2, f2, Wt2, O2_, O1_, O2_);
    transpose_scale<<<dim3(16, 1), dim3(32, 8), 0, stream>>>(v3, f3, Wt3, O3_, O2_, 16);

    gemm1<<<dim3(5, 4, B_), 128, 0, stream>>>(spike, Wt1, zA);        // zA = z1 (f64)
    scan12<<<256, 64, 0, stream>>>(zA, d1, sB, sums + 0);             // sB = s1 (f32)
    gemm2<<<dim3(M_ / 64, 4), 128, 0, stream>>>(sB, Wt2, zA);         // zA = z2
    scan12<<<256, 64, 0, stream>>>(zA, d2, sB, sums + 1);             // sB = s2
    gemm3<<<(M_ + 255) / 256, 256, 0, stream>>>(sB, Wt3, z3b);        // z3b = z3
    scan3<<<B_, 64, 0, stream>>>(z3b, d3, out, sums + 2);
    finalize<<<1, 64, 0, stream>>>(sums, out + (size_t)B_ * O3_ * T_);
}

// Round 5
// 1153.604 us; speedup vs baseline: 1.2917x; 1.2917x over previous
//
#include <hip/hip_runtime.h>

#define B_   32
#define T_   300
#define C1_  2312
#define O1_  512
#define O2_  512
#define O3_  10
#define M_   (B_*T_)   // 9600

// ---------------- weight prep (all f64) ----------------

__global__ void calc_f(const float* __restrict__ v, const float* __restrict__ g,
                       double* __restrict__ f, int O, int C) {
    int o = blockIdx.x;
    const float* row = v + (size_t)o * C;
    double s = 0.0;
    for (int c = threadIdx.x; c < C; c += blockDim.x) {
        double x = (double)row[c];
        s += x * x;
    }
    for (int off = 32; off; off >>= 1) s += __shfl_down(s, off);
    __shared__ double wsum[4];
    int lane = threadIdx.x & 63, wv = threadIdx.x >> 6;
    if (lane == 0) wsum[wv] = s;
    __syncthreads();
    if (threadIdx.x == 0) {
        double tot = 0.0;
        for (int i = 0; i < (int)(blockDim.x >> 6); ++i) tot += wsum[i];
        f[o] = (double)g[o] / sqrt(tot);
    }
}

// wt[c*ldo + o] = v[o*C + c] * f[o]   (double)
__global__ void transpose_scale(const float* __restrict__ v, const double* __restrict__ f,
                                double* __restrict__ wt, int O, int C, int ldo) {
    __shared__ double tile[32][33];
    int c0 = blockIdx.x * 32, o0 = blockIdx.y * 32;
    int tx = threadIdx.x, ty = threadIdx.y;
    for (int k = 0; k < 4; ++k) {
        int o = o0 + ty + k * 8, c = c0 + tx;
        double val = 0.0;
        if (o < O && c < C) val = (double)v[(size_t)o * C + c] * f[o];
        tile[ty + k * 8][tx] = val;
    }
    __syncthreads();
    for (int k = 0; k < 4; ++k) {
        int c = c0 + ty + k * 8, o = o0 + tx;
        if (c < C && o < O) wt[(size_t)c * ldo + o] = tile[tx][ty + k * 8];
    }
}

// ---------------- GEMM layer 1 (f64) ----------------
// X: spike [B, C1, T] f32 ; Wt: [C1, O1] f64 ; Z: [B, T, O1] f64
// 256 threads, tile 128o x 64t, micro 8o x 4t.
//   o = o0 + to + 16*i  (to = tid&15)  -> wf read: 16 lanes -> 16 distinct
//       double-banks, conflict-free (4-way same-address broadcast).
//   t = t0 + tt*4 + j   (tt = tid>>4)  -> xf read: phase-uniform broadcast.
// Staging: lanes write CONSECUTIVE double2s (2-way bank aliasing = free).
__global__ __launch_bounds__(256) void gemm1(const float* __restrict__ X,
                                             const double* __restrict__ Wt,
                                             double* __restrict__ Z) {
    __shared__ double Ws[16][128];   // [k][o]
    __shared__ double Xs[16][64];    // [k][t]
    int b  = blockIdx.z;
    int o0 = blockIdx.y * 128;
    int t0 = blockIdx.x * 64;
    int tid = threadIdx.x;
    int to = tid & 15, tt = tid >> 4;
    double acc[8][4];
#pragma unroll
    for (int i = 0; i < 8; ++i)
#pragma unroll
        for (int j = 0; j < 4; ++j) acc[i][j] = 0.0;
    const float* Xb = X + (size_t)b * C1_ * T_;
    for (int c0 = 0; c0 < C1_; c0 += 16) {
#pragma unroll
        for (int h = 0; h < 2; ++h) {   // Xs: 1024 doubles, 2 double2/thread, linear
            int idx = h * 512 + tid * 2;
            int i = idx >> 6, j = idx & 63;
            int c = c0 + i, t = t0 + j;
            double2 val; val.x = 0.0; val.y = 0.0;
            if (c < C1_ && t < T_) {   // t even, T_ even -> t+1 also valid
                float2 fv = *(const float2*)(Xb + (size_t)c * T_ + t);
                val.x = (double)fv.x; val.y = (double)fv.y;
            }
            *(double2*)(&Xs[i][j]) = val;
        }
#pragma unroll
        for (int h = 0; h < 4; ++h) {   // Ws: 2048 doubles, 4 double2/thread, linear
            int idx = h * 512 + tid * 2;
            int i = idx >> 7, o = idx & 127;
            int c = c0 + i;
            double2 val; val.x = 0.0; val.y = 0.0;
            if (c < C1_) val = *(const double2*)(Wt + (size_t)c * O1_ + o0 + o);
            *(double2*)(&Ws[i][o]) = val;
        }
        __syncthreads();
#pragma unroll
        for (int k = 0; k < 16; ++k) {
            double wf[8], xf[4];
#pragma unroll
            for (int i = 0; i < 8; ++i) wf[i] = Ws[k][to + 16 * i];
            *(double2*)(&xf[0]) = *(const double2*)(&Xs[k][tt * 4]);
            *(double2*)(&xf[2]) = *(const double2*)(&Xs[k][tt * 4 + 2]);
#pragma unroll
            for (int i = 0; i < 8; ++i)
#pragma unroll
                for (int j = 0; j < 4; ++j) acc[i][j] = fma(wf[i], xf[j], acc[i][j]);
        }
        __syncthreads();
    }
#pragma unroll
    for (int j = 0; j < 4; ++j) {
        int t = t0 + tt * 4 + j;
        if (t < T_) {
            double* dst = Z + ((size_t)b * T_ + t) * O1_ + o0;
#pragma unroll
            for (int i = 0; i < 8; ++i) dst[to + 16 * i] = acc[i][j];
        }
    }
}

// ---------------- GEMM layer 2 (f64) ----------------
// A: s1 [M, 512] f32 (exact 0/1) ; Wt: [512, 512] f64 ; Z: [M, 512] f64
// Same structure: tile 128o x 64m, micro 8o x 4m. A staged [m][k] with +1 pad
// (write banks (m + 4*(l&3) + u) % 16 = all-16-distinct; reads phase-broadcast).
__global__ __launch_bounds__(256) void gemm2(const float* __restrict__ A,
                                             const double* __restrict__ Wt,
                                             double* __restrict__ Z) {
    __shared__ double Ws[16][128];   // [k][o]
    __shared__ double As[64][17];    // [m][k] padded
    int m0 = blockIdx.x * 64;
    int o0 = blockIdx.y * 128;
    int tid = threadIdx.x;
    int to = tid & 15, tm = tid >> 4;
    double acc[8][4];
#pragma unroll
    for (int i = 0; i < 8; ++i)
#pragma unroll
        for (int j = 0; j < 4; ++j) acc[i][j] = 0.0;
    for (int c0 = 0; c0 < 512; c0 += 16) {
        {   // As: thread (m = tid>>2, ch = (tid&3)*4) reads float4, scalar LDS writes
            int m = tid >> 2, ch = (tid & 3) * 4;
            float4 v = *(const float4*)(A + (size_t)(m0 + m) * 512 + c0 + ch);
            As[m][ch + 0] = (double)v.x; As[m][ch + 1] = (double)v.y;
            As[m][ch + 2] = (double)v.z; As[m][ch + 3] = (double)v.w;
        }
#pragma unroll
        for (int h = 0; h < 4; ++h) {   // Ws: linear double2, 2-way = free
            int idx = h * 512 + tid * 2;
            int i = idx >> 7, o = idx & 127;
            *(double2*)(&Ws[i][o]) = *(const double2*)(Wt + (size_t)(c0 + i) * 512 + o0 + o);
        }
        __syncthreads();
#pragma unroll
        for (int k = 0; k < 16; ++k) {
            double wf[8], xf[4];
#pragma unroll
            for (int i = 0; i < 8; ++i) wf[i] = Ws[k][to + 16 * i];
#pragma unroll
            for (int j = 0; j < 4; ++j) xf[j] = As[tm * 4 + j][k];
#pragma unroll
            for (int i = 0; i < 8; ++i)
#pragma unroll
                for (int j = 0; j < 4; ++j) acc[i][j] = fma(wf[i], xf[j], acc[i][j]);
        }
        __syncthreads();
    }
#pragma unroll
    for (int j = 0; j < 4; ++j) {
        double* dst = Z + (size_t)(m0 + tm * 4 + j) * 512 + o0;
#pragma unroll
        for (int i = 0; i < 8; ++i) dst[to + 16 * i] = acc[i][j];
    }
}

// ---------------- GEMM layer 3 (f64 acc) ----------------
__global__ __launch_bounds__(256) void gemm3(const float* __restrict__ A,
                                             const double* __restrict__ Wt,
                                             double* __restrict__ Z) {
    __shared__ double w[512 * 16];
    for (int e = threadIdx.x; e < 4096; e += 256)
        ((double2*)w)[e] = ((const double2*)Wt)[e];
    __syncthreads();
    int m = blockIdx.x * 256 + threadIdx.x;
    if (m >= M_) return;
    double acc[O3_];
#pragma unroll
    for (int o = 0; o < O3_; ++o) acc[o] = 0.0;
    const float4* Ar = (const float4*)(A + (size_t)m * 512);
    for (int cq = 0; cq < 128; ++cq) {
        float4 a = Ar[cq];
        float av[4] = {a.x, a.y, a.z, a.w};
#pragma unroll
        for (int u = 0; u < 4; ++u)
#pragma unroll
            for (int o = 0; o < O3_; ++o) acc[o] += (double)av[u] * w[(cq * 4 + u) * 16 + o];
    }
    double* dst = Z + (size_t)m * 16;
#pragma unroll
    for (int o = 0; o < O3_; ++o) dst[o] = acc[o];
}

// ---------------- LIF scan + delay, layers 1/2 (O=512, f64 state) ----------------
__global__ void scan12(const double* __restrict__ Zin,  // [B, T, 512] f64
                       const int* __restrict__ delay,   // [512]
                       float* __restrict__ Sout,        // [B, T, 512] f32 spikes
                       float* __restrict__ sumOut) {
    int blk = blockIdx.x;
    int o = (blk & 7) * 64 + threadIdx.x;
    int b = blk >> 3;
    const double* z = Zin + (size_t)b * T_ * O1_ + o;
    float* s = Sout + (size_t)b * T_ * O1_ + o;
    int d = delay[o];
    for (int t = 0; t < d; ++t) s[(size_t)t * O1_] = 0.f;
    double cur = 0.0, vol = 0.0;
    float cnt = 0.f;
    for (int t4 = 0; t4 < T_; t4 += 4) {
        double zb[4];
#pragma unroll
        for (int u = 0; u < 4; ++u) zb[u] = z[(size_t)(t4 + u) * O1_];
#pragma unroll
        for (int u = 0; u < 4; ++u) {
            int t = t4 + u;
            cur = cur * 0.75 + zb[u];
            vol = vol * 0.97 + cur;
            float sp = (vol >= 1.25) ? 1.f : 0.f;
            if (sp > 0.f) vol = 0.0;
            int tw = t + d;
            if (tw < T_) { s[(size_t)tw * O1_] = sp; cnt += sp; }
        }
    }
    for (int off = 32; off; off >>= 1) cnt += __shfl_down(cnt, off);
    if (threadIdx.x == 0) atomicAdd(sumOut, cnt);
}

// ---------------- LIF scan + delay, layer 3 (O=10, f64 state) ----------------
__global__ void scan3(const double* __restrict__ Z3,  // [M, 16] f64
                      const int* __restrict__ d3,     // [10]
                      float* __restrict__ out,        // d_out: [B, 10, 300] f32
                      float* __restrict__ sumOut) {
    __shared__ double zt[T_ * 16];
    int b = blockIdx.x;
    const double2* src = (const double2*)(Z3 + (size_t)b * T_ * 16);
    for (int e = threadIdx.x; e < T_ * 8; e += 64)
        ((double2*)zt)[e] = src[e];
    __syncthreads();
    int o = threadIdx.x;
    if (o < O3_) {
        int d = d3[o];
        float* dst = out + (size_t)b * O3_ * T_ + (size_t)o * T_;
        for (int t = 0; t < d; ++t) dst[t] = 0.f;
        double cur = 0.0, vol = 0.0;
        float cnt = 0.f;
        for (int t = 0; t < T_; ++t) {
            cur = cur * 0.75 + zt[t * 16 + o];
            vol = vol * 0.97 + cur;
            float sp = (vol >= 1.25) ? 1.f : 0.f;
            if (sp > 0.f) vol = 0.0;
            int tw = t + d;
            if (tw < T_) { dst[tw] = sp; cnt += sp; }
        }
        atomicAdd(sumOut, cnt);
    }
}

__global__ void finalize(const float* __restrict__ sums, float* __restrict__ out) {
    if (threadIdx.x == 0) {
        out[0] = (float)((double)sums[0] / (double)(B_ * O1_ * T_));
        out[1] = (float)((double)sums[1] / (double)(B_ * O2_ * T_));
        out[2] = (float)((double)sums[2] / (double)(B_ * O3_ * T_));
    }
}

extern "C" void kernel_launch(void* const* d_in, const int* in_sizes, int n_in,
                              void* d_out, int out_size, void* d_ws, size_t ws_size,
                              hipStream_t stream) {
    const float* spike = (const float*)d_in[0];
    const float* v1 = (const float*)d_in[1];
    const float* g1 = (const float*)d_in[2];
    const float* v2 = (const float*)d_in[3];
    const float* g2 = (const float*)d_in[4];
    const float* v3 = (const float*)d_in[5];
    const float* g3 = (const float*)d_in[6];
    const int* d1 = (const int*)d_in[7];
    const int* d2 = (const int*)d_in[8];
    const int* d3 = (const int*)d_in[9];
    float* out = (float*)d_out;

    // Workspace (same layout as R3/R4 pass): ~72 MB total.
    double* dw = (double*)d_ws;
    size_t off = 0;
    double* f1  = dw + off; off += 512;
    double* f2  = dw + off; off += 512;
    double* f3  = dw + off; off += 16;
    double* Wt1 = dw + off; off += (size_t)C1_ * O1_;
    double* Wt2 = dw + off; off += 512 * 512;
    double* Wt3 = dw + off; off += 512 * 16;
    double* zA  = dw + off; off += (size_t)M_ * 512;
    double* z3b = dw + off; off += (size_t)M_ * 16;
    float* fw = (float*)(dw + off);
    float* sB   = fw;                        // f32 spikes, M*512
    float* sums = fw + (size_t)M_ * 512;     // 4 floats
    (void)ws_size; (void)out_size; (void)in_sizes; (void)n_in;

    hipMemsetAsync(sums, 0, 4 * sizeof(float), stream);

    calc_f<<<512, 256, 0, stream>>>(v1, g1, f1, O1_, C1_);
    calc_f<<<512, 256, 0, stream>>>(v2, g2, f2, O2_, O1_);
    calc_f<<<O3_, 256, 0, stream>>>(v3, g3, f3, O3_, O2_);

    transpose_scale<<<dim3((C1_ + 31) / 32, 16), dim3(32, 8), 0, stream>>>(v1, f1, Wt1, O1_, C1_, O1_);
    transpose_scale<<<dim3(16, 16), dim3(32, 8), 0, stream>>>(v2, f2, Wt2, O2_, O1_, O2_);
    transpose_scale<<<dim3(16, 1), dim3(32, 8), 0, stream>>>(v3, f3, Wt3, O3_, O2_, 16);

    gemm1<<<dim3(5, 4, B_), 256, 0, stream>>>(spike, Wt1, zA);        // zA = z1 (f64)
    scan12<<<256, 64, 0, stream>>>(zA, d1, sB, sums + 0);             // sB = s1 (f32)
    gemm2<<<dim3(M_ / 64, 4), 256, 0, stream>>>(sB, Wt2, zA);         // zA = z2
    scan12<<<256, 64, 0, stream>>>(zA, d2, sB, sums + 1);             // sB = s2
    gemm3<<<(M_ + 255) / 256, 256, 0, stream>>>(sB, Wt3, z3b);        // z3b = z3
    scan3<<<B_, 64, 0, stream>>>(z3b, d3, out, sums + 2);
    finalize<<<1, 64, 0, stream>>>(sums, out + (size_t)B_ * O3_ * T_);
}